// Round 1
// baseline (2070.098 us; speedup 1.0000x reference)
//
#include <hip/hip_runtime.h>

#define B_ 2
#define C_ 256
#define IC_ 128
#define N_ 4096
#define KSEL 2048

// workspace offsets (in floats)
#define OFF_THETA 0u
#define OFF_PHI   (1u << 20)
#define OFF_G     (2u << 20)
#define OFF_GW    (3u << 20)
#define OFF_GC    (4u << 20)
#define OFF_Y     (5u << 20)
#define OFF_MEAN  (7u << 20)
#define OFF_RSIG  ((7u << 20) + 256u)
#define OFF_CNT   ((7u << 20) + 512u)   // int[2]
#define OFF_LIST  ((7u << 20) + 516u)   // int[B_*N_]

__device__ __forceinline__ unsigned int f2u(float f) {
    unsigned int u = __float_as_uint(f);
    return (u & 0x80000000u) ? ~u : (u | 0x80000000u);
}

// ---------------------------------------------------------------------------
// Projections: theta/g (b,n,ic) and phi (b,ic,n) from x (b,c,n)
// grid (N/64, B), block 256
// ---------------------------------------------------------------------------
__global__ __launch_bounds__(256) void proj_kernel(
    const float* __restrict__ x,
    const float* __restrict__ Wg,  const float* __restrict__ bg,
    const float* __restrict__ Wth, const float* __restrict__ bth,
    const float* __restrict__ Wph, const float* __restrict__ bph,
    float* __restrict__ theta, float* __restrict__ g, float* __restrict__ phi)
{
    __shared__ float xs[32][64];
    const int b  = blockIdx.y;
    const int n0 = blockIdx.x * 64;
    const int t  = threadIdx.x;
    const int tn = t & 63, tg = t >> 6;

    float accT[32], accG[32], accP[32];
#pragma unroll
    for (int s = 0; s < 32; ++s) { accT[s] = 0.f; accG[s] = 0.f; accP[s] = 0.f; }

    const float* xb = x + (size_t)b * C_ * N_ + n0;
    for (int chunk = 0; chunk < 8; ++chunk) {
        __syncthreads();
#pragma unroll
        for (int s = 0; s < 8; ++s) {
            int e = t + 256 * s;
            int cc = e >> 6, col = e & 63;
            xs[cc][col] = xb[(size_t)(chunk * 32 + cc) * N_ + col];
        }
        __syncthreads();
        for (int cc = 0; cc < 32; ++cc) {
            float xv = xs[cc][tn];
            int cg = chunk * 32 + cc;
#pragma unroll
            for (int s = 0; s < 32; ++s) {
                int i = tg + 4 * s;   // wave-uniform -> scalar loads
                accT[s] = fmaf(Wth[i * C_ + cg], xv, accT[s]);
                accG[s] = fmaf(Wg [i * C_ + cg], xv, accG[s]);
                accP[s] = fmaf(Wph[i * C_ + cg], xv, accP[s]);
            }
        }
    }
    const int n = n0 + tn;
#pragma unroll
    for (int s = 0; s < 32; ++s) {
        int i = tg + 4 * s;
        theta[((size_t)b * N_ + n) * IC_ + i] = accT[s] + bth[i];
        g    [((size_t)b * N_ + n) * IC_ + i] = accG[s] + bg[i];
        phi  [((size_t)b * IC_ + i) * N_ + n] = accP[s] + bph[i];
    }
}

// ---------------------------------------------------------------------------
// gW[b,n,j] = sum_i g[b,n,i] * Wgcn[i,j]
// grid (N, B), block 128
// ---------------------------------------------------------------------------
__global__ __launch_bounds__(128) void gw_kernel(
    const float* __restrict__ g, const float* __restrict__ Wgcn,
    float* __restrict__ gW)
{
    const int b = blockIdx.y, n = blockIdx.x, j = threadIdx.x;
    const float* grow = g + ((size_t)b * N_ + n) * IC_;
    float acc = 0.f;
#pragma unroll 8
    for (int i = 0; i < IC_; ++i)
        acc = fmaf(grow[i], Wgcn[i * IC_ + j], acc);
    gW[((size_t)b * N_ + n) * IC_ + j] = acc;
}

// ---------------------------------------------------------------------------
// hard-row compaction
// ---------------------------------------------------------------------------
__global__ __launch_bounds__(256) void compact_kernel(
    const float* __restrict__ hard_map, int* __restrict__ cnt,
    int* __restrict__ list)
{
    int idx = blockIdx.x * 256 + threadIdx.x;
    if (idx >= B_ * N_) return;
    int b = idx >> 12;
    int n = idx & (N_ - 1);
    if (hard_map[idx] > 0.5f) {
        int p = atomicAdd(&cnt[b], 1);
        list[b * N_ + p] = n;
    }
}

// ---------------------------------------------------------------------------
// Per 4 hard rows: scores, exact top-k radix select, softmax renorm, A @ gW
// grid (N/4, B), block 256
// ---------------------------------------------------------------------------
__global__ __launch_bounds__(256) void row_kernel(
    const float* __restrict__ theta, const float* __restrict__ phi,
    const float* __restrict__ gW, const int* __restrict__ cnt,
    const int* __restrict__ list, float* __restrict__ gc)
{
    __shared__ float sS[4][N_];          // 64 KB
    __shared__ float sTheta[4][IC_];
    __shared__ unsigned int sHist[256];
    __shared__ float sPart[2][4][IC_];
    __shared__ float sRed[8];
    __shared__ unsigned long long sPrefix;
    __shared__ unsigned int sRemain;

    const int b = blockIdx.y;
    const int count = cnt[b];
    const int base = blockIdx.x * 4;
    if (base >= count) return;
    const int t = threadIdx.x;
    const int lane = t & 63, wid = t >> 6;

    int rows[4];
#pragma unroll
    for (int r = 0; r < 4; ++r)
        rows[r] = (base + r < count) ? list[b * N_ + base + r] : -1;

    for (int e = t; e < 4 * IC_; e += 256) {
        int r = e >> 7, i = e & (IC_ - 1);
        sTheta[r][i] = (rows[r] >= 0)
            ? theta[((size_t)b * N_ + rows[r]) * IC_ + i] : 0.f;
    }
    __syncthreads();

    // ---- scores: S[r][m] = theta_r . phi[:,m] ----
    float acc0[16], acc1[16], acc2[16], acc3[16];
#pragma unroll
    for (int q = 0; q < 16; ++q) { acc0[q] = acc1[q] = acc2[q] = acc3[q] = 0.f; }
    const float* phiB = phi + (size_t)b * IC_ * N_ + t;
    for (int i = 0; i < IC_; ++i) {
        const float th0 = sTheta[0][i], th1 = sTheta[1][i];
        const float th2 = sTheta[2][i], th3 = sTheta[3][i];
        const float* prow = phiB + (size_t)i * N_;
#pragma unroll
        for (int q = 0; q < 16; ++q) {
            float pv = prow[256 * q];
            acc0[q] = fmaf(th0, pv, acc0[q]);
            acc1[q] = fmaf(th1, pv, acc1[q]);
            acc2[q] = fmaf(th2, pv, acc2[q]);
            acc3[q] = fmaf(th3, pv, acc3[q]);
        }
    }
#pragma unroll
    for (int q = 0; q < 16; ++q) {
        sS[0][t + 256 * q] = acc0[q];
        sS[1][t + 256 * q] = acc1[q];
        sS[2][t + 256 * q] = acc2[q];
        sS[3][t + 256 * q] = acc3[q];
    }
    __syncthreads();

    // ---- per-row: max, radix-select kth largest, Z & S_sel, weights ----
    for (int r = 0; r < 4; ++r) {
        if (rows[r] < 0) {
#pragma unroll
            for (int q = 0; q < 16; ++q) sS[r][t + 256 * q] = 0.f;
            __syncthreads();
            continue;
        }
        // row max
        float m = -3.4e38f;
#pragma unroll
        for (int q = 0; q < 16; ++q) m = fmaxf(m, sS[r][t + 256 * q]);
#pragma unroll
        for (int off = 32; off > 0; off >>= 1) m = fmaxf(m, __shfl_xor(m, off));
        if (lane == 0) sRed[wid] = m;
        __syncthreads();
        m = fmaxf(fmaxf(sRed[0], sRed[1]), fmaxf(sRed[2], sRed[3]));
        __syncthreads();

        // exact radix select (kth largest) in monotone-u32 space
        unsigned long long prefix = 0ull;
        unsigned int remain = KSEL;
        for (int d = 3; d >= 0; --d) {
            sHist[t] = 0u;
            __syncthreads();
#pragma unroll
            for (int q = 0; q < 16; ++q) {
                unsigned int u = f2u(sS[r][t + 256 * q]);
                if ((((unsigned long long)u) >> (8 * (d + 1))) == prefix)
                    atomicAdd(&sHist[(u >> (8 * d)) & 255u], 1u);
            }
            __syncthreads();
            if (t == 0) {
                unsigned int cum = 0u, bin = 0u;
                for (int bb = 255; bb >= 0; --bb) {
                    unsigned int cb = sHist[bb];
                    if (cum + cb >= remain) { bin = (unsigned)bb; break; }
                    cum += cb;
                }
                sPrefix = (prefix << 8) | bin;
                sRemain = remain - cum;
            }
            __syncthreads();
            prefix = sPrefix;
            remain = sRemain;
        }
        const unsigned int tu = (unsigned int)prefix;

        // Z (all), S_sel (selected), store selected e values
        float z = 0.f, ssel = 0.f;
#pragma unroll
        for (int q = 0; q < 16; ++q) {
            float v = sS[r][t + 256 * q];
            float e = expf(v - m);
            z += e;
            bool sel = (f2u(v) >= tu);
            if (sel) ssel += e;
            sS[r][t + 256 * q] = sel ? e : 0.f;
        }
#pragma unroll
        for (int off = 32; off > 0; off >>= 1) {
            z    += __shfl_xor(z, off);
            ssel += __shfl_xor(ssel, off);
        }
        if (lane == 0) { sRed[wid] = z; sRed[4 + wid] = ssel; }
        __syncthreads();
        float zt = sRed[0] + sRed[1] + sRed[2] + sRed[3];
        float st = sRed[4] + sRed[5] + sRed[6] + sRed[7];
        float inv = 1.f / (st + 1e-6f * zt);
        __syncthreads();
#pragma unroll
        for (int q = 0; q < 16; ++q) sS[r][t + 256 * q] *= inv;
        __syncthreads();
    }

    // ---- gc[r,i] = relu( sum_j p[r][j] * gW[j,i] ) ----
    const int i = t & (IC_ - 1);
    const int h = t >> 7;
    const float* gWB = gW + (size_t)b * N_ * IC_ + i;
    float a0 = 0.f, a1 = 0.f, a2 = 0.f, a3 = 0.f;
    const int j0 = h * 2048;
    for (int j = j0; j < j0 + 2048; ++j) {
        float w = gWB[(size_t)j * IC_];
        a0 = fmaf(sS[0][j], w, a0);
        a1 = fmaf(sS[1][j], w, a1);
        a2 = fmaf(sS[2][j], w, a2);
        a3 = fmaf(sS[3][j], w, a3);
    }
    sPart[h][0][i] = a0; sPart[h][1][i] = a1;
    sPart[h][2][i] = a2; sPart[h][3][i] = a3;
    __syncthreads();
#pragma unroll
    for (int rr = 0; rr < 2; ++rr) {
        int r = h + 2 * rr;
        float val = sPart[0][r][i] + sPart[1][r][i];
        if (rows[r] >= 0)
            gc[((size_t)b * N_ + rows[r]) * IC_ + i] = fmaxf(val, 0.f);
    }
}

// ---------------------------------------------------------------------------
// y[b,c,n] = Wout[c,:] . gc[b,n,:] + bout[c]
// grid (N/64, B), block 256
// ---------------------------------------------------------------------------
__global__ __launch_bounds__(256) void y_kernel(
    const float* __restrict__ gc, const float* __restrict__ Wout,
    const float* __restrict__ bout, float* __restrict__ y)
{
    __shared__ float gl[64][IC_ + 1];
    const int b = blockIdx.y, n0 = blockIdx.x * 64, t = threadIdx.x;
    for (int e = t; e < 64 * IC_; e += 256) {
        int nn = e >> 7, ii = e & (IC_ - 1);
        gl[nn][ii] = gc[((size_t)b * N_ + n0 + nn) * IC_ + ii];
    }
    __syncthreads();
    const int nn = t & 63, cg = t >> 6;
    for (int cc = 0; cc < 64; ++cc) {
        const int c = cg * 64 + cc;
        const float* wr = Wout + c * IC_;
        float acc = bout[c];
#pragma unroll 16
        for (int i = 0; i < IC_; ++i) acc = fmaf(wr[i], gl[nn][i], acc);
        y[((size_t)b * C_ + c) * N_ + n0 + nn] = acc;
    }
}

// ---------------------------------------------------------------------------
// BatchNorm stats per channel (training-mode, population var)
// ---------------------------------------------------------------------------
__global__ __launch_bounds__(256) void bn_stats_kernel(
    const float* __restrict__ y, float* __restrict__ mean,
    float* __restrict__ rsig)
{
    __shared__ float sr[8];
    const int c = blockIdx.x, t = threadIdx.x;
    const int lane = t & 63, wid = t >> 6;
    float s = 0.f, ss = 0.f;
    for (int b = 0; b < B_; ++b) {
        const float* yr = y + ((size_t)b * C_ + c) * N_;
        for (int n = t; n < N_; n += 256) {
            float v = yr[n];
            s += v; ss = fmaf(v, v, ss);
        }
    }
#pragma unroll
    for (int off = 32; off > 0; off >>= 1) {
        s  += __shfl_xor(s, off);
        ss += __shfl_xor(ss, off);
    }
    if (lane == 0) { sr[wid] = s; sr[4 + wid] = ss; }
    __syncthreads();
    if (t == 0) {
        float st  = sr[0] + sr[1] + sr[2] + sr[3];
        float sst = sr[4] + sr[5] + sr[6] + sr[7];
        float mu  = st / (float)(B_ * N_);
        float var = sst / (float)(B_ * N_) - mu * mu;
        mean[c] = mu;
        rsig[c] = rsqrtf(var + 1e-5f);
    }
}

// ---------------------------------------------------------------------------
// out = x + gamma*(y-mean)*rsig + beta
// ---------------------------------------------------------------------------
__global__ __launch_bounds__(256) void final_kernel(
    const float* __restrict__ x, const float* __restrict__ y,
    const float* __restrict__ mean, const float* __restrict__ rsig,
    const float* __restrict__ gamma, const float* __restrict__ beta,
    float* __restrict__ out)
{
    int idx = blockIdx.x * 256 + threadIdx.x;
    if (idx >= B_ * C_ * N_) return;
    int c = (idx >> 12) & (C_ - 1);
    out[idx] = x[idx] + fmaf(gamma[c], (y[idx] - mean[c]) * rsig[c], beta[c]);
}

extern "C" void kernel_launch(void* const* d_in, const int* in_sizes, int n_in,
                              void* d_out, int out_size, void* d_ws, size_t ws_size,
                              hipStream_t stream)
{
    const float* x     = (const float*)d_in[0];
    const float* hard  = (const float*)d_in[1];
    const float* Wg    = (const float*)d_in[2];
    const float* bg    = (const float*)d_in[3];
    const float* Wth   = (const float*)d_in[4];
    const float* bth   = (const float*)d_in[5];
    const float* Wph   = (const float*)d_in[6];
    const float* bph   = (const float*)d_in[7];
    const float* Wgcn  = (const float*)d_in[8];
    const float* Wout  = (const float*)d_in[9];
    const float* bout  = (const float*)d_in[10];
    const float* gamma = (const float*)d_in[11];
    const float* beta  = (const float*)d_in[12];
    float* out = (float*)d_out;
    float* ws  = (float*)d_ws;

    float* theta = ws + OFF_THETA;
    float* phi   = ws + OFF_PHI;
    float* g     = ws + OFF_G;
    float* gW    = ws + OFF_GW;
    float* gc    = ws + OFF_GC;
    float* y     = ws + OFF_Y;
    float* mean  = ws + OFF_MEAN;
    float* rsig  = ws + OFF_RSIG;
    int*   cnt   = (int*)(ws + OFF_CNT);
    int*   list  = (int*)(ws + OFF_LIST);

    hipMemsetAsync(cnt, 0, 2 * sizeof(int), stream);
    hipMemsetAsync(gc, 0, (size_t)B_ * N_ * IC_ * sizeof(float), stream);

    proj_kernel<<<dim3(N_ / 64, B_), 256, 0, stream>>>(
        x, Wg, bg, Wth, bth, Wph, bph, theta, g, phi);
    gw_kernel<<<dim3(N_, B_), 128, 0, stream>>>(g, Wgcn, gW);
    compact_kernel<<<dim3(B_ * N_ / 256), 256, 0, stream>>>(hard, cnt, list);
    row_kernel<<<dim3(N_ / 4, B_), 256, 0, stream>>>(theta, phi, gW, cnt, list, gc);
    y_kernel<<<dim3(N_ / 64, B_), 256, 0, stream>>>(gc, Wout, bout, y);
    bn_stats_kernel<<<dim3(C_), 256, 0, stream>>>(y, mean, rsig);
    final_kernel<<<dim3(B_ * C_ * N_ / 256), 256, 0, stream>>>(
        x, y, mean, rsig, gamma, beta, out);
}

// Round 2
// 894.449 us; speedup vs baseline: 2.3144x; 2.3144x over previous
//
#include <hip/hip_runtime.h>

#define B_ 2
#define C_ 256
#define IC_ 128
#define N_ 4096
#define KSEL 2048

// workspace offsets (in floats)
#define OFF_THETA 0u
#define OFF_PHI   (1u << 20)
#define OFF_G     (2u << 20)
#define OFF_GW    (3u << 20)
#define OFF_GC    (4u << 20)
#define OFF_Y     (5u << 20)
#define OFF_MEAN  (7u << 20)
#define OFF_RSIG  ((7u << 20) + 256u)
#define OFF_CNT   ((7u << 20) + 512u)   // int[2]
#define OFF_LIST  ((7u << 20) + 516u)   // int[B_*N_]

__device__ __forceinline__ unsigned int f2u(float f) {
    unsigned int u = __float_as_uint(f);
    return (u & 0x80000000u) ? ~u : (u | 0x80000000u);
}

// ---------------------------------------------------------------------------
// Projections as tiled GEMM: out[384, N] = W[384,256] x X[256,N] per batch.
// blockIdx.x = output 64-chunk (0-1 theta, 2-3 g, 4-5 phi), y = n-tile, z = b.
// 256 threads, 4x4 register tile each -> 16 accumulators (no spill).
// ---------------------------------------------------------------------------
__global__ __launch_bounds__(256) void proj_kernel(
    const float* __restrict__ x,
    const float* __restrict__ Wg,  const float* __restrict__ bg,
    const float* __restrict__ Wth, const float* __restrict__ bth,
    const float* __restrict__ Wph, const float* __restrict__ bph,
    float* __restrict__ theta, float* __restrict__ g, float* __restrict__ phi)
{
    __shared__ float Xs[32][65];
    __shared__ float Ws[64][33];
    const int oc    = blockIdx.x;       // 0..5
    const int n0    = blockIdx.y * 64;
    const int b     = blockIdx.z;
    const int proj  = oc >> 1;
    const int orow0 = (oc & 1) * 64;
    const float* W    = (proj == 0) ? Wth : (proj == 1) ? Wg : Wph;
    const float* bias = (proj == 0) ? bth : (proj == 1) ? bg : bph;

    const int t  = threadIdx.x;
    const int tx = t & 15;
    const int ty = t >> 4;

    float acc[4][4];
#pragma unroll
    for (int u = 0; u < 4; ++u)
#pragma unroll
        for (int v = 0; v < 4; ++v) acc[u][v] = 0.f;

    const float* xb = x + (size_t)b * C_ * N_ + n0;
    for (int k0 = 0; k0 < C_; k0 += 32) {
#pragma unroll
        for (int s = 0; s < 8; ++s) {
            int e = t + 256 * s;
            int kk = e >> 6, col = e & 63;
            Xs[kk][col] = xb[(size_t)(k0 + kk) * N_ + col];
        }
#pragma unroll
        for (int s = 0; s < 8; ++s) {
            int e = t + 256 * s;
            int row = e >> 5, kk = e & 31;
            Ws[row][kk] = W[(orow0 + row) * C_ + k0 + kk];
        }
        __syncthreads();
#pragma unroll
        for (int kk = 0; kk < 32; ++kk) {
            float a[4], xv[4];
#pragma unroll
            for (int u = 0; u < 4; ++u) a[u] = Ws[ty + 16 * u][kk];
#pragma unroll
            for (int v = 0; v < 4; ++v) xv[v] = Xs[kk][tx + 16 * v];
#pragma unroll
            for (int u = 0; u < 4; ++u)
#pragma unroll
                for (int v = 0; v < 4; ++v)
                    acc[u][v] = fmaf(a[u], xv[v], acc[u][v]);
        }
        __syncthreads();
    }

#pragma unroll
    for (int u = 0; u < 4; ++u) {
        const int o = orow0 + ty + 16 * u;
        const float bo = bias[o];
#pragma unroll
        for (int v = 0; v < 4; ++v) {
            const int n = n0 + tx + 16 * v;
            const float val = acc[u][v] + bo;
            if (proj == 2) {
                phi[((size_t)b * IC_ + o) * N_ + n] = val;
            } else {
                float* dst = (proj == 0) ? theta : g;
                dst[((size_t)b * N_ + n) * IC_ + o] = val;
            }
        }
    }
}

// ---------------------------------------------------------------------------
// gW[b,n,j] = sum_i g[b,n,i] * Wgcn[i,j]; 32 n-rows per block, Wgcn reuse x16
// ---------------------------------------------------------------------------
__global__ __launch_bounds__(256) void gw_kernel(
    const float* __restrict__ g, const float* __restrict__ Wgcn,
    float* __restrict__ gW)
{
    __shared__ float gs[32][IC_];
    const int b = blockIdx.y, n0 = blockIdx.x * 32;
    const int t = threadIdx.x;
    const int j = t & 127, h = t >> 7;

    for (int e = t; e < 32 * IC_; e += 256)
        gs[e >> 7][e & 127] = g[((size_t)b * N_ + n0 + (e >> 7)) * IC_ + (e & 127)];
    __syncthreads();

    float acc[16];
#pragma unroll
    for (int r = 0; r < 16; ++r) acc[r] = 0.f;
    for (int i = 0; i < IC_; ++i) {
        float w = Wgcn[i * IC_ + j];
#pragma unroll
        for (int r = 0; r < 16; ++r)
            acc[r] = fmaf(gs[h * 16 + r][i], w, acc[r]);
    }
#pragma unroll
    for (int r = 0; r < 16; ++r)
        gW[((size_t)b * N_ + n0 + h * 16 + r) * IC_ + j] = acc[r];
}

// ---------------------------------------------------------------------------
// hard-row compaction
// ---------------------------------------------------------------------------
__global__ __launch_bounds__(256) void compact_kernel(
    const float* __restrict__ hard_map, int* __restrict__ cnt,
    int* __restrict__ list)
{
    int idx = blockIdx.x * 256 + threadIdx.x;
    if (idx >= B_ * N_) return;
    int b = idx >> 12;
    int n = idx & (N_ - 1);
    if (hard_map[idx] > 0.5f) {
        int p = atomicAdd(&cnt[b], 1);
        list[b * N_ + p] = n;
    }
}

// ---------------------------------------------------------------------------
// Per 4 hard rows: scores, exact top-k radix select, softmax renorm, A @ gW
// grid (N/4, B), block 256
// ---------------------------------------------------------------------------
__global__ __launch_bounds__(256) void row_kernel(
    const float* __restrict__ theta, const float* __restrict__ phi,
    const float* __restrict__ gW, const int* __restrict__ cnt,
    const int* __restrict__ list, float* __restrict__ gc)
{
    __shared__ float sS[4][N_];          // 64 KB
    __shared__ float sTheta[4][IC_];
    __shared__ unsigned int sHist[256];
    __shared__ float sPart[2][4][IC_];
    __shared__ float sRed[8];
    __shared__ unsigned long long sPrefix;
    __shared__ unsigned int sRemain;

    const int b = blockIdx.y;
    const int count = cnt[b];
    const int base = blockIdx.x * 4;
    if (base >= count) return;
    const int t = threadIdx.x;
    const int lane = t & 63, wid = t >> 6;

    int rows[4];
#pragma unroll
    for (int r = 0; r < 4; ++r)
        rows[r] = (base + r < count) ? list[b * N_ + base + r] : -1;

    for (int e = t; e < 4 * IC_; e += 256) {
        int r = e >> 7, i = e & (IC_ - 1);
        sTheta[r][i] = (rows[r] >= 0)
            ? theta[((size_t)b * N_ + rows[r]) * IC_ + i] : 0.f;
    }
    __syncthreads();

    // ---- scores: S[r][m] = theta_r . phi[:,m] ----
    float acc0[16], acc1[16], acc2[16], acc3[16];
#pragma unroll
    for (int q = 0; q < 16; ++q) { acc0[q] = acc1[q] = acc2[q] = acc3[q] = 0.f; }
    const float* phiB = phi + (size_t)b * IC_ * N_ + t;
    for (int i = 0; i < IC_; ++i) {
        const float th0 = sTheta[0][i], th1 = sTheta[1][i];
        const float th2 = sTheta[2][i], th3 = sTheta[3][i];
        const float* prow = phiB + (size_t)i * N_;
#pragma unroll
        for (int q = 0; q < 16; ++q) {
            float pv = prow[256 * q];
            acc0[q] = fmaf(th0, pv, acc0[q]);
            acc1[q] = fmaf(th1, pv, acc1[q]);
            acc2[q] = fmaf(th2, pv, acc2[q]);
            acc3[q] = fmaf(th3, pv, acc3[q]);
        }
    }
#pragma unroll
    for (int q = 0; q < 16; ++q) {
        sS[0][t + 256 * q] = acc0[q];
        sS[1][t + 256 * q] = acc1[q];
        sS[2][t + 256 * q] = acc2[q];
        sS[3][t + 256 * q] = acc3[q];
    }
    __syncthreads();

    // ---- per-row: max, radix-select kth largest, Z & S_sel, weights ----
    for (int r = 0; r < 4; ++r) {
        if (rows[r] < 0) {
#pragma unroll
            for (int q = 0; q < 16; ++q) sS[r][t + 256 * q] = 0.f;
            __syncthreads();
            continue;
        }
        // row max
        float m = -3.4e38f;
#pragma unroll
        for (int q = 0; q < 16; ++q) m = fmaxf(m, sS[r][t + 256 * q]);
#pragma unroll
        for (int off = 32; off > 0; off >>= 1) m = fmaxf(m, __shfl_xor(m, off));
        if (lane == 0) sRed[wid] = m;
        __syncthreads();
        m = fmaxf(fmaxf(sRed[0], sRed[1]), fmaxf(sRed[2], sRed[3]));
        __syncthreads();

        // exact radix select (kth largest) in monotone-u32 space
        unsigned long long prefix = 0ull;
        unsigned int remain = KSEL;
        for (int d = 3; d >= 0; --d) {
            sHist[t] = 0u;
            __syncthreads();
#pragma unroll
            for (int q = 0; q < 16; ++q) {
                unsigned int u = f2u(sS[r][t + 256 * q]);
                if ((((unsigned long long)u) >> (8 * (d + 1))) == prefix)
                    atomicAdd(&sHist[(u >> (8 * d)) & 255u], 1u);
            }
            __syncthreads();
            if (t == 0) {
                unsigned int cum = 0u, bin = 0u;
                for (int bb = 255; bb >= 0; --bb) {
                    unsigned int cb = sHist[bb];
                    if (cum + cb >= remain) { bin = (unsigned)bb; break; }
                    cum += cb;
                }
                sPrefix = (prefix << 8) | bin;
                sRemain = remain - cum;
            }
            __syncthreads();
            prefix = sPrefix;
            remain = sRemain;
        }
        const unsigned int tu = (unsigned int)prefix;

        // Z (all), S_sel (selected), store selected e values
        float z = 0.f, ssel = 0.f;
#pragma unroll
        for (int q = 0; q < 16; ++q) {
            float v = sS[r][t + 256 * q];
            float e = expf(v - m);
            z += e;
            bool sel = (f2u(v) >= tu);
            if (sel) ssel += e;
            sS[r][t + 256 * q] = sel ? e : 0.f;
        }
#pragma unroll
        for (int off = 32; off > 0; off >>= 1) {
            z    += __shfl_xor(z, off);
            ssel += __shfl_xor(ssel, off);
        }
        if (lane == 0) { sRed[wid] = z; sRed[4 + wid] = ssel; }
        __syncthreads();
        float zt = sRed[0] + sRed[1] + sRed[2] + sRed[3];
        float st = sRed[4] + sRed[5] + sRed[6] + sRed[7];
        float inv = 1.f / (st + 1e-6f * zt);
        __syncthreads();
#pragma unroll
        for (int q = 0; q < 16; ++q) sS[r][t + 256 * q] *= inv;
        __syncthreads();
    }

    // ---- gc[r,i] = relu( sum_j p[r][j] * gW[j,i] ) ----
    const int i = t & (IC_ - 1);
    const int h = t >> 7;
    const float* gWB = gW + (size_t)b * N_ * IC_ + i;
    float a0 = 0.f, a1 = 0.f, a2 = 0.f, a3 = 0.f;
    const int j0 = h * 2048;
    for (int j = j0; j < j0 + 2048; ++j) {
        float w = gWB[(size_t)j * IC_];
        a0 = fmaf(sS[0][j], w, a0);
        a1 = fmaf(sS[1][j], w, a1);
        a2 = fmaf(sS[2][j], w, a2);
        a3 = fmaf(sS[3][j], w, a3);
    }
    sPart[h][0][i] = a0; sPart[h][1][i] = a1;
    sPart[h][2][i] = a2; sPart[h][3][i] = a3;
    __syncthreads();
#pragma unroll
    for (int rr = 0; rr < 2; ++rr) {
        int r = h + 2 * rr;
        float val = sPart[0][r][i] + sPart[1][r][i];
        if (rows[r] >= 0)
            gc[((size_t)b * N_ + rows[r]) * IC_ + i] = fmaxf(val, 0.f);
    }
}

// ---------------------------------------------------------------------------
// y[b,c,n] = Wout[c,:] . gc[b,n,:] + bout[c]
// ---------------------------------------------------------------------------
__global__ __launch_bounds__(256) void y_kernel(
    const float* __restrict__ gc, const float* __restrict__ Wout,
    const float* __restrict__ bout, float* __restrict__ y)
{
    __shared__ float gl[64][IC_ + 1];
    const int b = blockIdx.y, n0 = blockIdx.x * 64, t = threadIdx.x;
    for (int e = t; e < 64 * IC_; e += 256) {
        int nn = e >> 7, ii = e & (IC_ - 1);
        gl[nn][ii] = gc[((size_t)b * N_ + n0 + nn) * IC_ + ii];
    }
    __syncthreads();
    const int nn = t & 63, cg = t >> 6;
    for (int cc = 0; cc < 64; ++cc) {
        const int c = cg * 64 + cc;
        const float* wr = Wout + c * IC_;
        float acc = bout[c];
#pragma unroll 16
        for (int i = 0; i < IC_; ++i) acc = fmaf(wr[i], gl[nn][i], acc);
        y[((size_t)b * C_ + c) * N_ + n0 + nn] = acc;
    }
}

// ---------------------------------------------------------------------------
// BatchNorm stats per channel (training-mode, population var)
// ---------------------------------------------------------------------------
__global__ __launch_bounds__(256) void bn_stats_kernel(
    const float* __restrict__ y, float* __restrict__ mean,
    float* __restrict__ rsig)
{
    __shared__ float sr[8];
    const int c = blockIdx.x, t = threadIdx.x;
    const int lane = t & 63, wid = t >> 6;
    float s = 0.f, ss = 0.f;
    for (int b = 0; b < B_; ++b) {
        const float* yr = y + ((size_t)b * C_ + c) * N_;
        for (int n = t; n < N_; n += 256) {
            float v = yr[n];
            s += v; ss = fmaf(v, v, ss);
        }
    }
#pragma unroll
    for (int off = 32; off > 0; off >>= 1) {
        s  += __shfl_xor(s, off);
        ss += __shfl_xor(ss, off);
    }
    if (lane == 0) { sr[wid] = s; sr[4 + wid] = ss; }
    __syncthreads();
    if (t == 0) {
        float st  = sr[0] + sr[1] + sr[2] + sr[3];
        float sst = sr[4] + sr[5] + sr[6] + sr[7];
        float mu  = st / (float)(B_ * N_);
        float var = sst / (float)(B_ * N_) - mu * mu;
        mean[c] = mu;
        rsig[c] = rsqrtf(var + 1e-5f);
    }
}

// ---------------------------------------------------------------------------
// out = x + gamma*(y-mean)*rsig + beta
// ---------------------------------------------------------------------------
__global__ __launch_bounds__(256) void final_kernel(
    const float* __restrict__ x, const float* __restrict__ y,
    const float* __restrict__ mean, const float* __restrict__ rsig,
    const float* __restrict__ gamma, const float* __restrict__ beta,
    float* __restrict__ out)
{
    int idx = blockIdx.x * 256 + threadIdx.x;
    if (idx >= B_ * C_ * N_) return;
    int c = (idx >> 12) & (C_ - 1);
    out[idx] = x[idx] + fmaf(gamma[c], (y[idx] - mean[c]) * rsig[c], beta[c]);
}

extern "C" void kernel_launch(void* const* d_in, const int* in_sizes, int n_in,
                              void* d_out, int out_size, void* d_ws, size_t ws_size,
                              hipStream_t stream)
{
    const float* x     = (const float*)d_in[0];
    const float* hard  = (const float*)d_in[1];
    const float* Wg    = (const float*)d_in[2];
    const float* bg    = (const float*)d_in[3];
    const float* Wth   = (const float*)d_in[4];
    const float* bth   = (const float*)d_in[5];
    const float* Wph   = (const float*)d_in[6];
    const float* bph   = (const float*)d_in[7];
    const float* Wgcn  = (const float*)d_in[8];
    const float* Wout  = (const float*)d_in[9];
    const float* bout  = (const float*)d_in[10];
    const float* gamma = (const float*)d_in[11];
    const float* beta  = (const float*)d_in[12];
    float* out = (float*)d_out;
    float* ws  = (float*)d_ws;

    float* theta = ws + OFF_THETA;
    float* phi   = ws + OFF_PHI;
    float* g     = ws + OFF_G;
    float* gW    = ws + OFF_GW;
    float* gc    = ws + OFF_GC;
    float* y     = ws + OFF_Y;
    float* mean  = ws + OFF_MEAN;
    float* rsig  = ws + OFF_RSIG;
    int*   cnt   = (int*)(ws + OFF_CNT);
    int*   list  = (int*)(ws + OFF_LIST);

    hipMemsetAsync(cnt, 0, 2 * sizeof(int), stream);
    hipMemsetAsync(gc, 0, (size_t)B_ * N_ * IC_ * sizeof(float), stream);

    proj_kernel<<<dim3(6, N_ / 64, B_), 256, 0, stream>>>(
        x, Wg, bg, Wth, bth, Wph, bph, theta, g, phi);
    gw_kernel<<<dim3(N_ / 32, B_), 256, 0, stream>>>(g, Wgcn, gW);
    compact_kernel<<<dim3(B_ * N_ / 256), 256, 0, stream>>>(hard, cnt, list);
    row_kernel<<<dim3(N_ / 4, B_), 256, 0, stream>>>(theta, phi, gW, cnt, list, gc);
    y_kernel<<<dim3(N_ / 64, B_), 256, 0, stream>>>(gc, Wout, bout, y);
    bn_stats_kernel<<<dim3(C_), 256, 0, stream>>>(y, mean, rsig);
    final_kernel<<<dim3(B_ * C_ * N_ / 256), 256, 0, stream>>>(
        x, y, mean, rsig, gamma, beta, out);
}

// Round 3
// 641.975 us; speedup vs baseline: 3.2246x; 1.3933x over previous
//
#include <hip/hip_runtime.h>

#define B_ 2
#define C_ 256
#define IC_ 128
#define N_ 4096
#define KSEL 2048
#define QROWS 1024

// workspace offsets (in floats) — total ~42 MB
#define OFF_THETA 0u
#define OFF_PHI   (1u<<20)
#define OFF_GW    (2u<<20)
#define OFF_GC    (3u<<20)
#define OFF_Y     (4u<<20)
#define OFF_S     (6u<<20)                 // QROWS x N_ = 4M floats
#define OFF_WEFF  (10u<<20)
#define OFF_BEFF  ((10u<<20)+32768u)
#define OFF_STATS ((10u<<20)+33024u)       // QROWS float4
#define OFF_MEAN  ((10u<<20)+40960u)
#define OFF_RSIG  ((10u<<20)+41216u)
#define OFF_CNT   ((10u<<20)+41472u)
#define OFF_LIST  ((10u<<20)+41728u)

__device__ __forceinline__ unsigned int f2u(float f) {
    unsigned int u = __float_as_uint(f);
    return (u & 0x80000000u) ? ~u : (u | 0x80000000u);
}

// ---------------------------------------------------------------------------
// Weff[o][c] = sum_i Wgcn[i][o] * Wg[i][c];  beff[o] = sum_i Wgcn[i][o]*bg[i]
// ---------------------------------------------------------------------------
__global__ __launch_bounds__(256) void weff_kernel(
    const float* __restrict__ Wg, const float* __restrict__ bg,
    const float* __restrict__ Wgcn, float* __restrict__ Weff,
    float* __restrict__ beff)
{
    const int o = blockIdx.x, c = threadIdx.x;
    float acc = 0.f;
    for (int i = 0; i < IC_; ++i)
        acc = fmaf(Wgcn[i * IC_ + o], Wg[i * C_ + c], acc);
    Weff[o * C_ + c] = acc;
    if (c == 0) {
        float bacc = 0.f;
        for (int i = 0; i < IC_; ++i)
            bacc = fmaf(Wgcn[i * IC_ + o], bg[i], bacc);
        beff[o] = bacc;
    }
}

// ---------------------------------------------------------------------------
// Projections as tiled GEMM: {theta, gW(=Weff proj), phi} from x.
// blockIdx.x = output 64-chunk (0-1 theta, 2-3 gW, 4-5 phi), y = n-tile, z = b
// ---------------------------------------------------------------------------
__global__ __launch_bounds__(256) void proj_kernel(
    const float* __restrict__ x,
    const float* __restrict__ Wth, const float* __restrict__ bth,
    const float* __restrict__ Weff, const float* __restrict__ beff,
    const float* __restrict__ Wph, const float* __restrict__ bph,
    float* __restrict__ theta, float* __restrict__ gW, float* __restrict__ phi)
{
    __shared__ float Xs[32][65];
    __shared__ float Ws[64][33];
    const int oc    = blockIdx.x;
    const int n0    = blockIdx.y * 64;
    const int b     = blockIdx.z;
    const int proj  = oc >> 1;
    const int orow0 = (oc & 1) * 64;
    const float* W    = (proj == 0) ? Wth : (proj == 1) ? Weff : Wph;
    const float* bias = (proj == 0) ? bth : (proj == 1) ? beff : bph;

    const int t  = threadIdx.x;
    const int tx = t & 15;
    const int ty = t >> 4;

    float acc[4][4];
#pragma unroll
    for (int u = 0; u < 4; ++u)
#pragma unroll
        for (int v = 0; v < 4; ++v) acc[u][v] = 0.f;

    const float* xb = x + (size_t)b * C_ * N_ + n0;
    for (int k0 = 0; k0 < C_; k0 += 32) {
#pragma unroll
        for (int s = 0; s < 8; ++s) {
            int e = t + 256 * s;
            int kk = e >> 6, col = e & 63;
            Xs[kk][col] = xb[(size_t)(k0 + kk) * N_ + col];
        }
#pragma unroll
        for (int s = 0; s < 8; ++s) {
            int e = t + 256 * s;
            int row = e >> 5, kk = e & 31;
            Ws[row][kk] = W[(orow0 + row) * C_ + k0 + kk];
        }
        __syncthreads();
#pragma unroll
        for (int kk = 0; kk < 32; ++kk) {
            float a[4], xv[4];
#pragma unroll
            for (int u = 0; u < 4; ++u) a[u] = Ws[ty + 16 * u][kk];
#pragma unroll
            for (int v = 0; v < 4; ++v) xv[v] = Xs[kk][tx + 16 * v];
#pragma unroll
            for (int u = 0; u < 4; ++u)
#pragma unroll
                for (int v = 0; v < 4; ++v)
                    acc[u][v] = fmaf(a[u], xv[v], acc[u][v]);
        }
        __syncthreads();
    }

#pragma unroll
    for (int u = 0; u < 4; ++u) {
        const int o = orow0 + ty + 16 * u;
        const float bo = bias[o];
#pragma unroll
        for (int v = 0; v < 4; ++v) {
            const int n = n0 + tx + 16 * v;
            const float val = acc[u][v] + bo;
            if (proj == 2) {
                phi[((size_t)b * IC_ + o) * N_ + n] = val;
            } else {
                float* dst = (proj == 0) ? theta : gW;
                dst[((size_t)b * N_ + n) * IC_ + o] = val;
            }
        }
    }
}

// ---------------------------------------------------------------------------
// hard-row compaction
// ---------------------------------------------------------------------------
__global__ __launch_bounds__(256) void compact_kernel(
    const float* __restrict__ hard_map, int* __restrict__ cnt,
    int* __restrict__ list)
{
    int idx = blockIdx.x * 256 + threadIdx.x;
    if (idx >= B_ * N_) return;
    int b = idx >> 12;
    int n = idx & (N_ - 1);
    if (hard_map[idx] > 0.5f) {
        int p = atomicAdd(&cnt[b], 1);
        list[b * N_ + p] = n;
    }
}

// ---------------------------------------------------------------------------
// S[lr][m] = theta[row(lr)] . phi[:,m] for one (batch, row-quarter) pass.
// 128x128 tile, 256 threads, 8x8 per thread. grid (32 mtiles, 8 rtiles)
// ---------------------------------------------------------------------------
__global__ __launch_bounds__(256) void score_kernel(
    const float* __restrict__ theta, const float* __restrict__ phi,
    const int* __restrict__ cnt, const int* __restrict__ list,
    float* __restrict__ S, int b, int r0base)
{
    __shared__ float Th[128][129];   // [r][k]
    __shared__ float Ph[128][128];   // [k][m]
    __shared__ int sIdx[128];

    const int count = cnt[b];
    const int lr0 = blockIdx.y * 128;
    if (r0base + lr0 >= count) return;
    const int m0 = blockIdx.x * 128;
    const int t = threadIdx.x;

    if (t < 128) {
        int gr = r0base + lr0 + t;
        sIdx[t] = (gr < count) ? list[b * N_ + gr] : -1;
    }
    __syncthreads();

    // stage theta rows (gathered) and phi tile, float4 global loads
    for (int s = 0; s < 16; ++s) {
        int e4 = t + 256 * s;
        int r = e4 >> 5, k4 = e4 & 31;
        int gr = sIdx[r];
        float4 v = make_float4(0.f, 0.f, 0.f, 0.f);
        if (gr >= 0)
            v = *(const float4*)&theta[((size_t)b * N_ + gr) * IC_ + k4 * 4];
        Th[r][k4 * 4 + 0] = v.x; Th[r][k4 * 4 + 1] = v.y;
        Th[r][k4 * 4 + 2] = v.z; Th[r][k4 * 4 + 3] = v.w;
    }
    for (int s = 0; s < 16; ++s) {
        int e4 = t + 256 * s;
        int i = e4 >> 5, m4 = e4 & 31;
        float4 v = *(const float4*)&phi[((size_t)b * IC_ + i) * N_ + m0 + m4 * 4];
        *(float4*)&Ph[i][m4 * 4] = v;
    }
    __syncthreads();

    const int tx = t & 15, ty = t >> 4;
    float acc[8][8];
#pragma unroll
    for (int u = 0; u < 8; ++u)
#pragma unroll
        for (int v = 0; v < 8; ++v) acc[u][v] = 0.f;

#pragma unroll 2
    for (int k = 0; k < 128; ++k) {
        float a[8];
#pragma unroll
        for (int u = 0; u < 8; ++u) a[u] = Th[ty * 8 + u][k];
        const float4 b0 = *(const float4*)&Ph[k][tx * 8];
        const float4 b1 = *(const float4*)&Ph[k][tx * 8 + 4];
        const float bb[8] = {b0.x, b0.y, b0.z, b0.w, b1.x, b1.y, b1.z, b1.w};
#pragma unroll
        for (int u = 0; u < 8; ++u)
#pragma unroll
            for (int v = 0; v < 8; ++v)
                acc[u][v] = fmaf(a[u], bb[v], acc[u][v]);
    }

#pragma unroll
    for (int u = 0; u < 8; ++u) {
        const int lr = lr0 + ty * 8 + u;
        *(float4*)&S[(size_t)lr * N_ + m0 + tx * 8] =
            make_float4(acc[u][0], acc[u][1], acc[u][2], acc[u][3]);
        *(float4*)&S[(size_t)lr * N_ + m0 + tx * 8 + 4] =
            make_float4(acc[u][4], acc[u][5], acc[u][6], acc[u][7]);
    }
}

// ---------------------------------------------------------------------------
// Per-row: exact kth-largest radix select + softmax stats.
// stats[lr] = {rowmax, bits(threshold), 1/(Ssel + 1e-6 Z), 0}
// ---------------------------------------------------------------------------
__global__ __launch_bounds__(256) void select_kernel(
    const float* __restrict__ S, const int* __restrict__ cnt,
    float4* __restrict__ stats, int b, int r0base)
{
    __shared__ unsigned int sHist[256];
    __shared__ unsigned int sWsum[4];
    __shared__ float sRed[8];
    __shared__ unsigned long long sPrefix;
    __shared__ unsigned int sRemain;

    const int lr = blockIdx.x;
    if (r0base + lr >= cnt[b]) return;
    const int t = threadIdx.x, lane = t & 63, wid = t >> 6;

    const float4* row = (const float4*)(S + (size_t)lr * N_);
    float4 v[4];
#pragma unroll
    for (int q = 0; q < 4; ++q) v[q] = row[t + 256 * q];

    float m = -3.4e38f;
#pragma unroll
    for (int q = 0; q < 4; ++q) {
        m = fmaxf(m, fmaxf(fmaxf(v[q].x, v[q].y), fmaxf(v[q].z, v[q].w)));
    }
#pragma unroll
    for (int off = 32; off > 0; off >>= 1) m = fmaxf(m, __shfl_xor(m, off));
    if (lane == 0) sRed[wid] = m;
    __syncthreads();
    m = fmaxf(fmaxf(sRed[0], sRed[1]), fmaxf(sRed[2], sRed[3]));

    unsigned long long prefix = 0ull;
    unsigned int remain = KSEL;
    for (int d = 3; d >= 0; --d) {
        __syncthreads();
        sHist[t] = 0u;
        __syncthreads();
        const float* pv = (const float*)v;
#pragma unroll
        for (int e = 0; e < 16; ++e) {
            unsigned int u = f2u(pv[e]);
            if ((((unsigned long long)u) >> (8 * (d + 1))) == prefix)
                atomicAdd(&sHist[(u >> (8 * d)) & 255u], 1u);
        }
        __syncthreads();
        unsigned int x = sHist[t], own = x;
#pragma unroll
        for (int off = 1; off < 64; off <<= 1) {
            unsigned int y = __shfl_down(x, off);
            if (lane + off < 64) x += y;
        }
        if (lane == 0) sWsum[wid] = x;
        __syncthreads();
        for (int w = wid + 1; w < 4; ++w) x += sWsum[w];
        unsigned int nxt = x - own;        // suffix starting at t+1
        if (x >= remain && nxt < remain) {
            sPrefix = (prefix << 8) | (unsigned long long)t;
            sRemain = remain - nxt;
        }
        __syncthreads();
        prefix = sPrefix;
        remain = sRemain;
    }
    const unsigned int tu = (unsigned int)prefix;

    float z = 0.f, ssel = 0.f;
    const float* pv = (const float*)v;
#pragma unroll
    for (int e = 0; e < 16; ++e) {
        float val = pv[e];
        float ex = expf(val - m);
        z += ex;
        if (f2u(val) >= tu) ssel += ex;
    }
#pragma unroll
    for (int off = 32; off > 0; off >>= 1) {
        z    += __shfl_xor(z, off);
        ssel += __shfl_xor(ssel, off);
    }
    __syncthreads();
    if (lane == 0) { sRed[wid] = z; sRed[4 + wid] = ssel; }
    __syncthreads();
    if (t == 0) {
        float zt = sRed[0] + sRed[1] + sRed[2] + sRed[3];
        float st = sRed[4] + sRed[5] + sRed[6] + sRed[7];
        stats[lr] = make_float4(m, __uint_as_float(tu),
                                1.f / (st + 1e-6f * zt), 0.f);
    }
}

// ---------------------------------------------------------------------------
// Split-K PV GEMM: gc_part[ks][lr][i] = sum_{j in ks-range} P[lr][j] gW[j][i]
// P recomputed on the fly from S + row stats. grid (16 rtiles, 16 ksplits)
// ---------------------------------------------------------------------------
__global__ __launch_bounds__(256) void pv_kernel(
    const float* __restrict__ S, const float* __restrict__ gW,
    const float4* __restrict__ stats, const int* __restrict__ cnt,
    float* __restrict__ gc_part, int b, int r0base)
{
    __shared__ float Pt[64][65];     // [j][r]
    __shared__ float Ws[64][128];    // [j][i]

    const int count = cnt[b];
    const int lr0 = blockIdx.x * 64;
    if (r0base + lr0 >= count) return;
    const int ks = blockIdx.y;
    const int j0 = ks * 256;
    const int t = threadIdx.x;
    const int rq = t >> 5, cq = t & 31;

    float acc[8][4];
#pragma unroll
    for (int u = 0; u < 8; ++u)
#pragma unroll
        for (int v = 0; v < 4; ++v) acc[u][v] = 0.f;

    for (int ch = 0; ch < 4; ++ch) {
        const int jc = j0 + ch * 64;
        __syncthreads();
        // P tile with on-the-fly select/softmax transform
#pragma unroll
        for (int s = 0; s < 4; ++s) {
            int e4 = t + 256 * s;            // 1024 float4 = 64r x 16
            int r = e4 >> 4, jf = e4 & 15;
            float p[4] = {0.f, 0.f, 0.f, 0.f};
            if (r0base + lr0 + r < count) {
                float4 rs = stats[lr0 + r];
                const unsigned int tu = __float_as_uint(rs.y);
                float4 sv = *(const float4*)&S[(size_t)(lr0 + r) * N_ + jc + jf * 4];
                const float* svp = (const float*)&sv;
#pragma unroll
                for (int q = 0; q < 4; ++q)
                    if (f2u(svp[q]) >= tu)
                        p[q] = expf(svp[q] - rs.x) * rs.z;
            }
#pragma unroll
            for (int q = 0; q < 4; ++q) Pt[jf * 4 + q][r] = p[q];
        }
        // gW tile
#pragma unroll
        for (int s = 0; s < 8; ++s) {
            int e4 = t + 256 * s;            // 2048 float4 = 64j x 32
            int j = e4 >> 5, i4 = e4 & 31;
            *(float4*)&Ws[j][i4 * 4] =
                *(const float4*)&gW[((size_t)b * N_ + jc + j) * IC_ + i4 * 4];
        }
        __syncthreads();

        for (int j = 0; j < 64; ++j) {
            float a[8];
#pragma unroll
            for (int u = 0; u < 8; ++u) a[u] = Pt[j][rq * 8 + u];
            const float4 w = *(const float4*)&Ws[j][cq * 4];
            const float wv[4] = {w.x, w.y, w.z, w.w};
#pragma unroll
            for (int u = 0; u < 8; ++u)
#pragma unroll
                for (int v = 0; v < 4; ++v)
                    acc[u][v] = fmaf(a[u], wv[v], acc[u][v]);
        }
    }

#pragma unroll
    for (int u = 0; u < 8; ++u) {
        int lr = lr0 + rq * 8 + u;
        *(float4*)&gc_part[((size_t)ks * QROWS + lr) * IC_ + cq * 4] =
            make_float4(acc[u][0], acc[u][1], acc[u][2], acc[u][3]);
    }
}

// ---------------------------------------------------------------------------
// reduce split-K partials, ReLU, scatter to gc[b][n][i]
// ---------------------------------------------------------------------------
__global__ __launch_bounds__(256) void scatter_kernel(
    const float* __restrict__ gc_part, const int* __restrict__ cnt,
    const int* __restrict__ list, float* __restrict__ gc, int b, int r0base)
{
    int idx = blockIdx.x * 256 + threadIdx.x;   // QROWS*IC_ threads
    int lr = idx >> 7, i = idx & 127;
    if (r0base + lr >= cnt[b]) return;
    float v = 0.f;
#pragma unroll
    for (int ks = 0; ks < 16; ++ks)
        v += gc_part[((size_t)ks * QROWS + lr) * IC_ + i];
    int n = list[b * N_ + r0base + lr];
    gc[((size_t)b * N_ + n) * IC_ + i] = fmaxf(v, 0.f);
}

// ---------------------------------------------------------------------------
// y[b,c,n] = Wout[c,:] . gc[b,n,:] + bout[c]
// ---------------------------------------------------------------------------
__global__ __launch_bounds__(256) void y_kernel(
    const float* __restrict__ gc, const float* __restrict__ Wout,
    const float* __restrict__ bout, float* __restrict__ y)
{
    __shared__ float gl[64][IC_ + 1];
    const int b = blockIdx.y, n0 = blockIdx.x * 64, t = threadIdx.x;
    for (int e = t; e < 64 * IC_; e += 256) {
        int nn = e >> 7, ii = e & (IC_ - 1);
        gl[nn][ii] = gc[((size_t)b * N_ + n0 + nn) * IC_ + ii];
    }
    __syncthreads();
    const int nn = t & 63, cg = t >> 6;
    for (int cc = 0; cc < 64; ++cc) {
        const int c = cg * 64 + cc;
        const float* wr = Wout + c * IC_;
        float acc = bout[c];
#pragma unroll 16
        for (int i = 0; i < IC_; ++i) acc = fmaf(wr[i], gl[nn][i], acc);
        y[((size_t)b * C_ + c) * N_ + n0 + nn] = acc;
    }
}

// ---------------------------------------------------------------------------
// BatchNorm stats per channel
// ---------------------------------------------------------------------------
__global__ __launch_bounds__(256) void bn_stats_kernel(
    const float* __restrict__ y, float* __restrict__ mean,
    float* __restrict__ rsig)
{
    __shared__ float sr[8];
    const int c = blockIdx.x, t = threadIdx.x;
    const int lane = t & 63, wid = t >> 6;
    float s = 0.f, ss = 0.f;
    for (int b = 0; b < B_; ++b) {
        const float* yr = y + ((size_t)b * C_ + c) * N_;
        for (int n = t; n < N_; n += 256) {
            float v = yr[n];
            s += v; ss = fmaf(v, v, ss);
        }
    }
#pragma unroll
    for (int off = 32; off > 0; off >>= 1) {
        s  += __shfl_xor(s, off);
        ss += __shfl_xor(ss, off);
    }
    if (lane == 0) { sr[wid] = s; sr[4 + wid] = ss; }
    __syncthreads();
    if (t == 0) {
        float st  = sr[0] + sr[1] + sr[2] + sr[3];
        float sst = sr[4] + sr[5] + sr[6] + sr[7];
        float mu  = st / (float)(B_ * N_);
        float var = sst / (float)(B_ * N_) - mu * mu;
        mean[c] = mu;
        rsig[c] = rsqrtf(var + 1e-5f);
    }
}

// ---------------------------------------------------------------------------
// out = x + gamma*(y-mean)*rsig + beta
// ---------------------------------------------------------------------------
__global__ __launch_bounds__(256) void final_kernel(
    const float* __restrict__ x, const float* __restrict__ y,
    const float* __restrict__ mean, const float* __restrict__ rsig,
    const float* __restrict__ gamma, const float* __restrict__ beta,
    float* __restrict__ out)
{
    int idx = blockIdx.x * 256 + threadIdx.x;
    if (idx >= B_ * C_ * N_) return;
    int c = (idx >> 12) & (C_ - 1);
    out[idx] = x[idx] + fmaf(gamma[c], (y[idx] - mean[c]) * rsig[c], beta[c]);
}

extern "C" void kernel_launch(void* const* d_in, const int* in_sizes, int n_in,
                              void* d_out, int out_size, void* d_ws, size_t ws_size,
                              hipStream_t stream)
{
    const float* x     = (const float*)d_in[0];
    const float* hard  = (const float*)d_in[1];
    const float* Wg    = (const float*)d_in[2];
    const float* bg    = (const float*)d_in[3];
    const float* Wth   = (const float*)d_in[4];
    const float* bth   = (const float*)d_in[5];
    const float* Wph   = (const float*)d_in[6];
    const float* bph   = (const float*)d_in[7];
    const float* Wgcn  = (const float*)d_in[8];
    const float* Wout  = (const float*)d_in[9];
    const float* bout  = (const float*)d_in[10];
    const float* gamma = (const float*)d_in[11];
    const float* beta  = (const float*)d_in[12];
    float* out = (float*)d_out;
    float* ws  = (float*)d_ws;

    float* theta = ws + OFF_THETA;
    float* phi   = ws + OFF_PHI;
    float* gW    = ws + OFF_GW;
    float* gc    = ws + OFF_GC;
    float* y     = ws + OFF_Y;
    float* S     = ws + OFF_S;
    float* Weff  = ws + OFF_WEFF;
    float* beff  = ws + OFF_BEFF;
    float4* stats = (float4*)(ws + OFF_STATS);
    float* mean  = ws + OFF_MEAN;
    float* rsig  = ws + OFF_RSIG;
    int*   cnt   = (int*)(ws + OFF_CNT);
    int*   list  = (int*)(ws + OFF_LIST);
    float* gc_part = out;   // d_out (8 MB) used as split-K scratch, fully
                            // overwritten by final_kernel at the end.

    hipMemsetAsync(cnt, 0, 2 * sizeof(int), stream);
    hipMemsetAsync(gc, 0, (size_t)B_ * N_ * IC_ * sizeof(float), stream);

    weff_kernel<<<dim3(IC_), 256, 0, stream>>>(Wg, bg, Wgcn, Weff, beff);
    proj_kernel<<<dim3(6, N_ / 64, B_), 256, 0, stream>>>(
        x, Wth, bth, Weff, beff, Wph, bph, theta, gW, phi);
    compact_kernel<<<dim3(B_ * N_ / 256), 256, 0, stream>>>(hard, cnt, list);

    for (int b = 0; b < B_; ++b) {
        for (int q = 0; q < N_ / QROWS; ++q) {
            const int r0 = q * QROWS;
            score_kernel<<<dim3(N_ / 128, QROWS / 128), 256, 0, stream>>>(
                theta, phi, cnt, list, S, b, r0);
            select_kernel<<<dim3(QROWS), 256, 0, stream>>>(S, cnt, stats, b, r0);
            pv_kernel<<<dim3(QROWS / 64, 16), 256, 0, stream>>>(
                S, gW, stats, cnt, gc_part, b, r0);
            scatter_kernel<<<dim3(QROWS * IC_ / 256), 256, 0, stream>>>(
                gc_part, cnt, list, gc, b, r0);
        }
    }

    y_kernel<<<dim3(N_ / 64, B_), 256, 0, stream>>>(gc, Wout, bout, y);
    bn_stats_kernel<<<dim3(C_), 256, 0, stream>>>(y, mean, rsig);
    final_kernel<<<dim3(B_ * C_ * N_ / 256), 256, 0, stream>>>(
        x, y, mean, rsig, gamma, beta, out);
}

// Round 4
// 394.658 us; speedup vs baseline: 5.2453x; 1.6267x over previous
//
#include <hip/hip_runtime.h>

#define B_ 2
#define C_ 256
#define IC_ 128
#define N_ 4096
#define KSEL 2048

// fixed workspace offsets (floats)
#define OFF_THETA 0u
#define OFF_PHI   1048576u
#define OFF_GW    2097152u
#define OFF_GC    3145728u
#define OFF_Y     4194304u          // 2M floats
#define OFF_WEFF  6291456u
#define OFF_BEFF  6324224u
#define OFF_MEAN  6324352u
#define OFF_RSIG  6324608u
#define OFF_CNT   6324864u
#define OFF_LIST  6324928u
#define OFF_DYN   6333440u          // S (+ gc_part) start here

__device__ __forceinline__ unsigned int f2u(float f) {
    unsigned int u = __float_as_uint(f);
    return (u & 0x80000000u) ? ~u : (u | 0x80000000u);
}

// ---------------------------------------------------------------------------
// Weff[o][c] = sum_i Wgcn[i][o] * Wg[i][c];  beff[o] = sum_i Wgcn[i][o]*bg[i]
// ---------------------------------------------------------------------------
__global__ __launch_bounds__(256) void weff_kernel(
    const float* __restrict__ Wg, const float* __restrict__ bg,
    const float* __restrict__ Wgcn, float* __restrict__ Weff,
    float* __restrict__ beff)
{
    const int o = blockIdx.x, c = threadIdx.x;
    float acc = 0.f;
    for (int i = 0; i < IC_; ++i)
        acc = fmaf(Wgcn[i * IC_ + o], Wg[i * C_ + c], acc);
    Weff[o * C_ + c] = acc;
    if (c == 0) {
        float bacc = 0.f;
        for (int i = 0; i < IC_; ++i)
            bacc = fmaf(Wgcn[i * IC_ + o], bg[i], bacc);
        beff[o] = bacc;
    }
}

// ---------------------------------------------------------------------------
// Projections as tiled GEMM: {theta, gW(=Weff proj), phi} from x.
// ---------------------------------------------------------------------------
__global__ __launch_bounds__(256) void proj_kernel(
    const float* __restrict__ x,
    const float* __restrict__ Wth, const float* __restrict__ bth,
    const float* __restrict__ Weff, const float* __restrict__ beff,
    const float* __restrict__ Wph, const float* __restrict__ bph,
    float* __restrict__ theta, float* __restrict__ gW, float* __restrict__ phi)
{
    __shared__ float Xs[32][65];
    __shared__ float Ws[64][33];
    const int oc    = blockIdx.x;
    const int n0    = blockIdx.y * 64;
    const int b     = blockIdx.z;
    const int proj  = oc >> 1;
    const int orow0 = (oc & 1) * 64;
    const float* W    = (proj == 0) ? Wth : (proj == 1) ? Weff : Wph;
    const float* bias = (proj == 0) ? bth : (proj == 1) ? beff : bph;

    const int t  = threadIdx.x;
    const int tx = t & 15;
    const int ty = t >> 4;

    float acc[4][4];
#pragma unroll
    for (int u = 0; u < 4; ++u)
#pragma unroll
        for (int v = 0; v < 4; ++v) acc[u][v] = 0.f;

    const float* xb = x + (size_t)b * C_ * N_ + n0;
    for (int k0 = 0; k0 < C_; k0 += 32) {
#pragma unroll
        for (int s = 0; s < 8; ++s) {
            int e = t + 256 * s;
            int kk = e >> 6, col = e & 63;
            Xs[kk][col] = xb[(size_t)(k0 + kk) * N_ + col];
        }
#pragma unroll
        for (int s = 0; s < 8; ++s) {
            int e = t + 256 * s;
            int row = e >> 5, kk = e & 31;
            Ws[row][kk] = W[(orow0 + row) * C_ + k0 + kk];
        }
        __syncthreads();
#pragma unroll
        for (int kk = 0; kk < 32; ++kk) {
            float a[4], xv[4];
#pragma unroll
            for (int u = 0; u < 4; ++u) a[u] = Ws[ty + 16 * u][kk];
#pragma unroll
            for (int v = 0; v < 4; ++v) xv[v] = Xs[kk][tx + 16 * v];
#pragma unroll
            for (int u = 0; u < 4; ++u)
#pragma unroll
                for (int v = 0; v < 4; ++v)
                    acc[u][v] = fmaf(a[u], xv[v], acc[u][v]);
        }
        __syncthreads();
    }

#pragma unroll
    for (int u = 0; u < 4; ++u) {
        const int o = orow0 + ty + 16 * u;
        const float bo = bias[o];
#pragma unroll
        for (int v = 0; v < 4; ++v) {
            const int n = n0 + tx + 16 * v;
            const float val = acc[u][v] + bo;
            if (proj == 2) {
                phi[((size_t)b * IC_ + o) * N_ + n] = val;
            } else {
                float* dst = (proj == 0) ? theta : gW;
                dst[((size_t)b * N_ + n) * IC_ + o] = val;
            }
        }
    }
}

// ---------------------------------------------------------------------------
// hard-row compaction
// ---------------------------------------------------------------------------
__global__ __launch_bounds__(256) void compact_kernel(
    const float* __restrict__ hard_map, int* __restrict__ cnt,
    int* __restrict__ list)
{
    int idx = blockIdx.x * 256 + threadIdx.x;
    if (idx >= B_ * N_) return;
    int b = idx >> 12;
    int n = idx & (N_ - 1);
    if (hard_map[idx] > 0.5f) {
        int p = atomicAdd(&cnt[b], 1);
        list[b * N_ + p] = n;
    }
}

// ---------------------------------------------------------------------------
// score: S[lr][m] = theta[row(lr)] . phi[:,m].  Tile 64r x 128m, K chunk 64.
// grid (N/128 mtiles, qr/64 rtiles). LDS ~50KB -> 3 blocks/CU resident cap.
// ---------------------------------------------------------------------------
__global__ __launch_bounds__(256) void score_kernel(
    const float* __restrict__ theta, const float* __restrict__ phi,
    const int* __restrict__ cnt, const int* __restrict__ list,
    float* __restrict__ S, int b, int r0base)
{
    __shared__ float Th[64][65];    // [r][k]
    __shared__ float Ph[64][132];   // [k][m]
    __shared__ int sIdx[64];

    const int count = cnt[b];
    const int lr0 = blockIdx.y * 64;
    if (r0base + lr0 >= count) return;
    const int m0 = blockIdx.x * 128;
    const int t = threadIdx.x;
    const int tx = t & 15, ty = t >> 4;

    if (t < 64) {
        int gr = r0base + lr0 + t;
        sIdx[t] = (gr < count) ? list[b * N_ + gr] : -1;
    }

    float acc[4][8];
#pragma unroll
    for (int u = 0; u < 4; ++u)
#pragma unroll
        for (int v = 0; v < 8; ++v) acc[u][v] = 0.f;

    for (int kc = 0; kc < IC_; kc += 64) {
        __syncthreads();
        // Th: 64r x 64k (gathered rows)
#pragma unroll
        for (int s = 0; s < 4; ++s) {
            int e4 = t + 256 * s;           // 1024 f4: r=e4>>4, k4=e4&15
            int r = e4 >> 4, k4 = e4 & 15;
            int gr = sIdx[r];
            float4 v = make_float4(0.f, 0.f, 0.f, 0.f);
            if (gr >= 0)
                v = *(const float4*)&theta[((size_t)b * N_ + gr) * IC_ + kc + k4 * 4];
            Th[r][k4 * 4 + 0] = v.x; Th[r][k4 * 4 + 1] = v.y;
            Th[r][k4 * 4 + 2] = v.z; Th[r][k4 * 4 + 3] = v.w;
        }
        // Ph: 64k x 128m
#pragma unroll
        for (int s = 0; s < 8; ++s) {
            int e4 = t + 256 * s;           // 2048 f4: k=e4>>5, m4=e4&31
            int kk = e4 >> 5, m4 = e4 & 31;
            *(float4*)&Ph[kk][m4 * 4] =
                *(const float4*)&phi[((size_t)b * IC_ + kc + kk) * N_ + m0 + m4 * 4];
        }
        __syncthreads();

#pragma unroll 4
        for (int k = 0; k < 64; ++k) {
            float a[4];
#pragma unroll
            for (int u = 0; u < 4; ++u) a[u] = Th[ty * 4 + u][k];
            const float4 p0 = *(const float4*)&Ph[k][tx * 8];
            const float4 p1 = *(const float4*)&Ph[k][tx * 8 + 4];
            const float pm[8] = {p0.x, p0.y, p0.z, p0.w, p1.x, p1.y, p1.z, p1.w};
#pragma unroll
            for (int u = 0; u < 4; ++u)
#pragma unroll
                for (int v = 0; v < 8; ++v)
                    acc[u][v] = fmaf(a[u], pm[v], acc[u][v]);
        }
    }

#pragma unroll
    for (int u = 0; u < 4; ++u) {
        const int lr = lr0 + ty * 4 + u;
        *(float4*)&S[(size_t)lr * N_ + m0 + tx * 8] =
            make_float4(acc[u][0], acc[u][1], acc[u][2], acc[u][3]);
        *(float4*)&S[(size_t)lr * N_ + m0 + tx * 8 + 4] =
            make_float4(acc[u][4], acc[u][5], acc[u][6], acc[u][7]);
    }
}

// ---------------------------------------------------------------------------
// select: per-row exact kth-largest radix select + softmax; writes P in-place
// into S (selected: exp(s-m)*inv, else 0). grid qr blocks.
// ---------------------------------------------------------------------------
__global__ __launch_bounds__(256) void select_kernel(
    float* __restrict__ S, const int* __restrict__ cnt, int b, int r0base)
{
    __shared__ unsigned int sHist[4][256];
    __shared__ unsigned int sWsum[4];
    __shared__ float sRed[8];
    __shared__ unsigned long long sPrefix;
    __shared__ unsigned int sRemain;

    const int lr = blockIdx.x;
    if (r0base + lr >= cnt[b]) return;
    const int t = threadIdx.x, lane = t & 63, wid = t >> 6;

    float4* row = (float4*)(S + (size_t)lr * N_);
    float4 v[4];
#pragma unroll
    for (int q = 0; q < 4; ++q) v[q] = row[t + 256 * q];

    float m = -3.4e38f;
#pragma unroll
    for (int q = 0; q < 4; ++q)
        m = fmaxf(m, fmaxf(fmaxf(v[q].x, v[q].y), fmaxf(v[q].z, v[q].w)));
#pragma unroll
    for (int off = 32; off > 0; off >>= 1) m = fmaxf(m, __shfl_xor(m, off));
    if (lane == 0) sRed[wid] = m;
    __syncthreads();
    m = fmaxf(fmaxf(sRed[0], sRed[1]), fmaxf(sRed[2], sRed[3]));

    unsigned long long prefix = 0ull;
    unsigned int remain = KSEL;
    for (int d = 3; d >= 0; --d) {
        __syncthreads();
#pragma unroll
        for (int w = 0; w < 4; ++w) sHist[w][t] = 0u;
        __syncthreads();
        const float* pv = (const float*)v;
#pragma unroll
        for (int e = 0; e < 16; ++e) {
            unsigned int u = f2u(pv[e]);
            if ((((unsigned long long)u) >> (8 * (d + 1))) == prefix)
                atomicAdd(&sHist[wid][(u >> (8 * d)) & 255u], 1u);
        }
        __syncthreads();
        unsigned int x = sHist[0][t] + sHist[1][t] + sHist[2][t] + sHist[3][t];
        unsigned int own = x;
#pragma unroll
        for (int off = 1; off < 64; off <<= 1) {
            unsigned int y = __shfl_down(x, off);
            if (lane + off < 64) x += y;
        }
        if (lane == 0) sWsum[wid] = x;
        __syncthreads();
        for (int w = wid + 1; w < 4; ++w) x += sWsum[w];
        unsigned int nxt = x - own;        // suffix starting at t+1
        if (x >= remain && nxt < remain) {
            sPrefix = (prefix << 8) | (unsigned long long)t;
            sRemain = remain - nxt;
        }
        __syncthreads();
        prefix = sPrefix;
        remain = sRemain;
    }
    const unsigned int tu = (unsigned int)prefix;

    float z = 0.f, ssel = 0.f;
    const float* pv = (const float*)v;
#pragma unroll
    for (int e = 0; e < 16; ++e) {
        float val = pv[e];
        float ex = expf(val - m);
        z += ex;
        if (f2u(val) >= tu) ssel += ex;
    }
#pragma unroll
    for (int off = 32; off > 0; off >>= 1) {
        z    += __shfl_xor(z, off);
        ssel += __shfl_xor(ssel, off);
    }
    __syncthreads();
    if (lane == 0) { sRed[wid] = z; sRed[4 + wid] = ssel; }
    __syncthreads();
    const float zt = sRed[0] + sRed[1] + sRed[2] + sRed[3];
    const float st = sRed[4] + sRed[5] + sRed[6] + sRed[7];
    const float inv = 1.f / (st + 1e-6f * zt);

    // write P in place
#pragma unroll
    for (int q = 0; q < 4; ++q) {
        float* c = (float*)&v[q];
        float4 p;
        float* pp = (float*)&p;
#pragma unroll
        for (int e = 0; e < 4; ++e)
            pp[e] = (f2u(c[e]) >= tu) ? expf(c[e] - m) * inv : 0.f;
        row[t + 256 * q] = p;
    }
}

// ---------------------------------------------------------------------------
// pv: pure split-K GEMM gc_part[ks][lr][i] = sum_{j in ks*256..} P[lr][j]*gW[j][i]
// grid (qr/64, 16). Tile 64r x 128i, j chunk 64.
// ---------------------------------------------------------------------------
__global__ __launch_bounds__(256) void pv_kernel(
    const float* __restrict__ S, const float* __restrict__ gW,
    const int* __restrict__ cnt, float* __restrict__ gc_part,
    int b, int r0base, int qr)
{
    __shared__ float Pt[64][65];     // [r][j]
    __shared__ float Ws[64][132];    // [j][i]

    const int count = cnt[b];
    const int lr0 = blockIdx.x * 64;
    if (r0base + lr0 >= count) return;
    const int ks = blockIdx.y;
    const int t = threadIdx.x;
    const int tx = t & 15, ty = t >> 4;

    float acc[4][8];
#pragma unroll
    for (int u = 0; u < 4; ++u)
#pragma unroll
        for (int v = 0; v < 8; ++v) acc[u][v] = 0.f;

    for (int jc = ks * 256; jc < ks * 256 + 256; jc += 64) {
        __syncthreads();
        // Pt: 64r x 64j from S (already transformed to P)
#pragma unroll
        for (int s = 0; s < 4; ++s) {
            int e4 = t + 256 * s;
            int r = e4 >> 4, j4 = e4 & 15;
            float4 p = *(const float4*)&S[(size_t)(lr0 + r) * N_ + jc + j4 * 4];
            Pt[r][j4 * 4 + 0] = p.x; Pt[r][j4 * 4 + 1] = p.y;
            Pt[r][j4 * 4 + 2] = p.z; Pt[r][j4 * 4 + 3] = p.w;
        }
        // Ws: 64j x 128i
#pragma unroll
        for (int s = 0; s < 8; ++s) {
            int e4 = t + 256 * s;
            int jj = e4 >> 5, i4 = e4 & 31;
            *(float4*)&Ws[jj][i4 * 4] =
                *(const float4*)&gW[((size_t)b * N_ + jc + jj) * IC_ + i4 * 4];
        }
        __syncthreads();

#pragma unroll 4
        for (int j = 0; j < 64; ++j) {
            float a[4];
#pragma unroll
            for (int u = 0; u < 4; ++u) a[u] = Pt[ty * 4 + u][j];
            const float4 w0 = *(const float4*)&Ws[j][tx * 8];
            const float4 w1 = *(const float4*)&Ws[j][tx * 8 + 4];
            const float wm[8] = {w0.x, w0.y, w0.z, w0.w, w1.x, w1.y, w1.z, w1.w};
#pragma unroll
            for (int u = 0; u < 4; ++u)
#pragma unroll
                for (int v = 0; v < 8; ++v)
                    acc[u][v] = fmaf(a[u], wm[v], acc[u][v]);
        }
    }

#pragma unroll
    for (int u = 0; u < 4; ++u) {
        const int lr = lr0 + ty * 4 + u;
        *(float4*)&gc_part[((size_t)ks * qr + lr) * IC_ + tx * 8] =
            make_float4(acc[u][0], acc[u][1], acc[u][2], acc[u][3]);
        *(float4*)&gc_part[((size_t)ks * qr + lr) * IC_ + tx * 8 + 4] =
            make_float4(acc[u][4], acc[u][5], acc[u][6], acc[u][7]);
    }
}

// ---------------------------------------------------------------------------
// reduce split-K partials, ReLU, scatter to gc[b][n][i]
// ---------------------------------------------------------------------------
__global__ __launch_bounds__(256) void scatter_kernel(
    const float* __restrict__ gc_part, const int* __restrict__ cnt,
    const int* __restrict__ list, float* __restrict__ gc,
    int b, int r0base, int qr)
{
    int idx = blockIdx.x * 256 + threadIdx.x;
    int lr = idx >> 7, i = idx & 127;
    if (r0base + lr >= cnt[b]) return;
    float v = 0.f;
#pragma unroll
    for (int ks = 0; ks < 16; ++ks)
        v += gc_part[((size_t)ks * qr + lr) * IC_ + i];
    int n = list[b * N_ + r0base + lr];
    gc[((size_t)b * N_ + n) * IC_ + i] = fmaxf(v, 0.f);
}

// ---------------------------------------------------------------------------
// y[b,c,n] = Wout[c,:] . gc[b,n,:] + bout[c].  Tile 64c x 64n, K chunk 32.
// grid (N/64, C/64, B) = 512 blocks, acc 4x4/thread.
// ---------------------------------------------------------------------------
__global__ __launch_bounds__(256) void y_kernel(
    const float* __restrict__ gc, const float* __restrict__ Wout,
    const float* __restrict__ bout, float* __restrict__ y)
{
    __shared__ float Wt[64][33];   // [c][k]
    __shared__ float Gt[32][68];   // [k][n]
    const int n0 = blockIdx.x * 64;
    const int c0 = blockIdx.y * 64;
    const int b  = blockIdx.z;
    const int t = threadIdx.x;
    const int tx = t & 15, ty = t >> 4;

    float acc[4][4];
#pragma unroll
    for (int u = 0; u < 4; ++u)
#pragma unroll
        for (int v = 0; v < 4; ++v) acc[u][v] = 0.f;

    for (int kc = 0; kc < IC_; kc += 32) {
        __syncthreads();
        // Wt: 64c x 32k
#pragma unroll
        for (int s = 0; s < 2; ++s) {
            int e4 = t + 256 * s;            // 512 f4: c=e4>>3, k4=e4&7
            int c = e4 >> 3, k4 = e4 & 7;
            float4 w = *(const float4*)&Wout[(size_t)(c0 + c) * IC_ + kc + k4 * 4];
            Wt[c][k4 * 4 + 0] = w.x; Wt[c][k4 * 4 + 1] = w.y;
            Wt[c][k4 * 4 + 2] = w.z; Wt[c][k4 * 4 + 3] = w.w;
        }
        // Gt: 32k x 64n (transposed from gc [n][i])
#pragma unroll
        for (int s = 0; s < 2; ++s) {
            int e4 = t + 256 * s;            // 512 f4: nn=e4>>3, k4=e4&7
            int nn = e4 >> 3, k4 = e4 & 7;
            float4 g = *(const float4*)&gc[((size_t)b * N_ + n0 + nn) * IC_ + kc + k4 * 4];
            Gt[k4 * 4 + 0][nn] = g.x; Gt[k4 * 4 + 1][nn] = g.y;
            Gt[k4 * 4 + 2][nn] = g.z; Gt[k4 * 4 + 3][nn] = g.w;
        }
        __syncthreads();

#pragma unroll 4
        for (int k = 0; k < 32; ++k) {
            float a[4];
#pragma unroll
            for (int u = 0; u < 4; ++u) a[u] = Wt[ty * 4 + u][k];
            const float4 g4 = *(const float4*)&Gt[k][tx * 4];
            const float gm[4] = {g4.x, g4.y, g4.z, g4.w};
#pragma unroll
            for (int u = 0; u < 4; ++u)
#pragma unroll
                for (int v = 0; v < 4; ++v)
                    acc[u][v] = fmaf(a[u], gm[v], acc[u][v]);
        }
    }

#pragma unroll
    for (int u = 0; u < 4; ++u) {
        const int c = c0 + ty * 4 + u;
        const float bo = bout[c];
        *(float4*)&y[((size_t)b * C_ + c) * N_ + n0 + tx * 4] =
            make_float4(acc[u][0] + bo, acc[u][1] + bo,
                        acc[u][2] + bo, acc[u][3] + bo);
    }
}

// ---------------------------------------------------------------------------
// BatchNorm stats per channel
// ---------------------------------------------------------------------------
__global__ __launch_bounds__(256) void bn_stats_kernel(
    const float* __restrict__ y, float* __restrict__ mean,
    float* __restrict__ rsig)
{
    __shared__ float sr[8];
    const int c = blockIdx.x, t = threadIdx.x;
    const int lane = t & 63, wid = t >> 6;
    float s = 0.f, ss = 0.f;
    for (int b = 0; b < B_; ++b) {
        const float* yr = y + ((size_t)b * C_ + c) * N_;
        for (int n = t; n < N_; n += 256) {
            float v = yr[n];
            s += v; ss = fmaf(v, v, ss);
        }
    }
#pragma unroll
    for (int off = 32; off > 0; off >>= 1) {
        s  += __shfl_xor(s, off);
        ss += __shfl_xor(ss, off);
    }
    if (lane == 0) { sr[wid] = s; sr[4 + wid] = ss; }
    __syncthreads();
    if (t == 0) {
        float st  = sr[0] + sr[1] + sr[2] + sr[3];
        float sst = sr[4] + sr[5] + sr[6] + sr[7];
        float mu  = st / (float)(B_ * N_);
        float var = sst / (float)(B_ * N_) - mu * mu;
        mean[c] = mu;
        rsig[c] = rsqrtf(var + 1e-5f);
    }
}

// ---------------------------------------------------------------------------
// out = x + gamma*(y-mean)*rsig + beta
// ---------------------------------------------------------------------------
__global__ __launch_bounds__(256) void final_kernel(
    const float* __restrict__ x, const float* __restrict__ y,
    const float* __restrict__ mean, const float* __restrict__ rsig,
    const float* __restrict__ gamma, const float* __restrict__ beta,
    float* __restrict__ out)
{
    int idx = blockIdx.x * 256 + threadIdx.x;
    if (idx >= B_ * C_ * N_) return;
    int c = (idx >> 12) & (C_ - 1);
    out[idx] = x[idx] + fmaf(gamma[c], (y[idx] - mean[c]) * rsig[c], beta[c]);
}

extern "C" void kernel_launch(void* const* d_in, const int* in_sizes, int n_in,
                              void* d_out, int out_size, void* d_ws, size_t ws_size,
                              hipStream_t stream)
{
    const float* x     = (const float*)d_in[0];
    const float* hard  = (const float*)d_in[1];
    const float* Wg    = (const float*)d_in[2];
    const float* bg    = (const float*)d_in[3];
    const float* Wth   = (const float*)d_in[4];
    const float* bth   = (const float*)d_in[5];
    const float* Wph   = (const float*)d_in[6];
    const float* bph   = (const float*)d_in[7];
    const float* Wgcn  = (const float*)d_in[8];
    const float* Wout  = (const float*)d_in[9];
    const float* bout  = (const float*)d_in[10];
    const float* gamma = (const float*)d_in[11];
    const float* beta  = (const float*)d_in[12];
    float* out = (float*)d_out;
    float* ws  = (float*)d_ws;

    float* theta = ws + OFF_THETA;
    float* phi   = ws + OFF_PHI;
    float* gW    = ws + OFF_GW;
    float* gc    = ws + OFF_GC;
    float* y     = ws + OFF_Y;
    float* Weff  = ws + OFF_WEFF;
    float* beff  = ws + OFF_BEFF;
    float* mean  = ws + OFF_MEAN;
    float* rsig  = ws + OFF_RSIG;
    int*   cnt   = (int*)(ws + OFF_CNT);
    int*   list  = (int*)(ws + OFF_LIST);

    // runtime-adaptive row-block size: pick largest that fits the workspace
    const size_t wsf = ws_size / sizeof(float);
    int qr = 1024;
    if (wsf >= OFF_DYN + 25165824u)       qr = 4096;  // S 16M + gc_part 8M
    else if (wsf >= OFF_DYN + 12582912u)  qr = 2048;  // S 8M  + gc_part 4M
    float* S = ws + OFF_DYN;
    float* gc_part = (qr == 1024) ? out : S + (size_t)qr * N_;
    // (qr==1024: d_out (2M floats) used as split-K scratch, fully overwritten
    //  by final_kernel at the end.)

    hipMemsetAsync(cnt, 0, 2 * sizeof(int), stream);
    hipMemsetAsync(gc, 0, (size_t)B_ * N_ * IC_ * sizeof(float), stream);

    weff_kernel<<<dim3(IC_), 256, 0, stream>>>(Wg, bg, Wgcn, Weff, beff);
    proj_kernel<<<dim3(6, N_ / 64, B_), 256, 0, stream>>>(
        x, Wth, bth, Weff, beff, Wph, bph, theta, gW, phi);
    compact_kernel<<<dim3(B_ * N_ / 256), 256, 0, stream>>>(hard, cnt, list);

    for (int b = 0; b < B_; ++b) {
        for (int r0 = 0; r0 < N_; r0 += qr) {
            score_kernel<<<dim3(N_ / 128, qr / 64), 256, 0, stream>>>(
                theta, phi, cnt, list, S, b, r0);
            select_kernel<<<dim3(qr), 256, 0, stream>>>(S, cnt, b, r0);
            pv_kernel<<<dim3(qr / 64, 16), 256, 0, stream>>>(
                S, gW, cnt, gc_part, b, r0, qr);
            scatter_kernel<<<dim3(qr / 2), 256, 0, stream>>>(
                gc_part, cnt, list, gc, b, r0, qr);
        }
    }

    y_kernel<<<dim3(N_ / 64, C_ / 64, B_), 256, 0, stream>>>(gc, Wout, bout, y);
    bn_stats_kernel<<<dim3(C_), 256, 0, stream>>>(y, mean, rsig);
    final_kernel<<<dim3(B_ * C_ * N_ / 256), 256, 0, stream>>>(
        x, y, mean, rsig, gamma, beta, out);
}